// Round 1
// baseline (1491.564 us; speedup 1.0000x reference)
//
#include <hip/hip_runtime.h>

#define N_NODES 100000
#define N_EDGES 1600000
#define EMB 128
#define BM 16
#define NSLAB 64
#define BN_EPS 1e-5f

// ---------------- K1: edge embed + gather + scatter-add ----------------
// 2 edges per 256-thread block; 128 threads per edge (one per dim).
__global__ __launch_bounds__(256) void edge_scatter_kernel(
    const float* __restrict__ node_feats,
    const float* __restrict__ ef0,
    const float* __restrict__ ef1,
    const int* __restrict__ src,
    const int* __restrict__ dst,
    const float* __restrict__ We0, const float* __restrict__ be0,
    const float* __restrict__ We1, const float* __restrict__ be1,
    float* __restrict__ agg)
{
    __shared__ float wS[10 * EMB];  // [0,768)=We0, [768,1152)=We1, [1152,1280)=be0+be1
    int tid = threadIdx.x;
    for (int i = tid; i < 6 * EMB; i += 256) wS[i] = We0[i];
    for (int i = tid; i < 3 * EMB; i += 256) wS[6 * EMB + i] = We1[i];
    if (tid < EMB) wS[9 * EMB + tid] = be0[tid] + be1[tid];
    __syncthreads();

    int e = blockIdx.x * 2 + (tid >> 7);
    if (e >= N_EDGES) return;
    int d = tid & 127;
    int s = src[e];
    int t = dst[e];
    const float* f0 = ef0 + (long)e * 6;
    const float* f1 = ef1 + (long)e * 3;

    float emb = wS[9 * EMB + d];
#pragma unroll
    for (int k = 0; k < 6; ++k) emb = fmaf(f0[k], wS[k * EMB + d], emb);
#pragma unroll
    for (int k = 0; k < 3; ++k) emb = fmaf(f1[k], wS[6 * EMB + k * EMB + d], emb);

    float val = node_feats[(long)s * EMB + d] + emb;
    atomicAdd(&agg[(long)t * EMB + d], val);
}

// ---------------- K2: fused MLP (in-place on agg rows) + BN partial stats ----
// One block = BM(16) node rows. agg tile -> LDS -> h1 (relu) -> LDS -> h2
// overwrites the same rows of the buffer. Partial sums go to slab-striped ws.
__global__ __launch_bounds__(256) void mlp_kernel(
    float* __restrict__ h,  // in: agg rows, out: h2 rows (d_out)
    const float* __restrict__ W1, const float* __restrict__ b1,
    const float* __restrict__ W2, const float* __restrict__ b2,
    float* __restrict__ stats)  // [NSLAB][2*EMB]
{
    __shared__ float aggS[BM][EMB];       // 8 KB
    __shared__ float h1S[BM][2 * EMB];    // 16 KB
    __shared__ float sredS[256];
    __shared__ float s2redS[256];

    int tid = threadIdx.x;
    long base = (long)blockIdx.x * BM;

    for (int i = tid; i < BM * EMB; i += 256)
        aggS[i >> 7][i & 127] = h[base * EMB + i];
    __syncthreads();

    // Layer 1: thread t owns output column t (0..255) for all 16 rows.
    {
        float acc[BM];
        float bias = b1[tid];
#pragma unroll
        for (int r = 0; r < BM; ++r) acc[r] = bias;
        for (int k = 0; k < EMB; ++k) {
            float w = W1[k * (2 * EMB) + tid];
#pragma unroll
            for (int r = 0; r < BM; ++r) acc[r] = fmaf(aggS[r][k], w, acc[r]);
        }
#pragma unroll
        for (int r = 0; r < BM; ++r) h1S[r][tid] = fmaxf(acc[r], 0.0f);
    }
    __syncthreads();

    // Layer 2: c = tid&127, rows (tid>>7)*8 .. +7
    {
        int c = tid & 127;
        int half = tid >> 7;
        float acc[8];
        float bias = b2[c];
#pragma unroll
        for (int r = 0; r < 8; ++r) acc[r] = bias;
        for (int k = 0; k < 2 * EMB; ++k) {
            float w = W2[k * EMB + c];
#pragma unroll
            for (int r = 0; r < 8; ++r) acc[r] = fmaf(h1S[half * 8 + r][k], w, acc[r]);
        }
        float s = 0.f, s2 = 0.f;
#pragma unroll
        for (int r = 0; r < 8; ++r) {
            h[(base + half * 8 + r) * EMB + c] = acc[r];
            s += acc[r];
            s2 = fmaf(acc[r], acc[r], s2);
        }
        sredS[tid] = s;
        s2redS[tid] = s2;
    }
    __syncthreads();
    if (tid < 128) {
        float s = sredS[tid] + sredS[tid + 128];
        float s2 = s2redS[tid] + s2redS[tid + 128];
        float* slab = stats + (blockIdx.x & (NSLAB - 1)) * (2 * EMB);
        atomicAdd(&slab[tid], s);
        atomicAdd(&slab[EMB + tid], s2);
    }
}

// ---------------- K3: BN finalize (one block, 128 threads) ----------------
__global__ __launch_bounds__(128) void bn_finalize_kernel(
    const float* __restrict__ stats,   // [NSLAB][2*EMB]
    const float* __restrict__ gamma, const float* __restrict__ beta,
    float* __restrict__ scaleshift)    // [2][EMB]
{
    int c = threadIdx.x;
    float s = 0.f, s2 = 0.f;
    for (int b = 0; b < NSLAB; ++b) {
        s += stats[b * (2 * EMB) + c];
        s2 += stats[b * (2 * EMB) + EMB + c];
    }
    float mean = s / (float)N_NODES;
    float var = s2 / (float)N_NODES - mean * mean;
    float sc = gamma[c] * rsqrtf(var + BN_EPS);
    scaleshift[c] = sc;
    scaleshift[EMB + c] = beta[c] - mean * sc;
}

// ---------------- K4: apply BN in place (float4) ----------------
__global__ __launch_bounds__(256) void bn_apply_kernel(
    float* __restrict__ h, const float* __restrict__ scaleshift)
{
    __shared__ float scS[EMB], shS[EMB];
    if (threadIdx.x < EMB) {
        scS[threadIdx.x] = scaleshift[threadIdx.x];
        shS[threadIdx.x] = scaleshift[EMB + threadIdx.x];
    }
    __syncthreads();
    long total = (long)N_NODES * EMB / 4;
    long stride = (long)gridDim.x * blockDim.x;
    for (long i = (long)blockIdx.x * blockDim.x + threadIdx.x; i < total; i += stride) {
        float4 v = ((float4*)h)[i];
        int c = (int)((i * 4) & 127);
        v.x = fmaf(v.x, scS[c + 0], shS[c + 0]);
        v.y = fmaf(v.y, scS[c + 1], shS[c + 1]);
        v.z = fmaf(v.z, scS[c + 2], shS[c + 2]);
        v.w = fmaf(v.w, scS[c + 3], shS[c + 3]);
        ((float4*)h)[i] = v;
    }
}

extern "C" void kernel_launch(void* const* d_in, const int* in_sizes, int n_in,
                              void* d_out, int out_size, void* d_ws, size_t ws_size,
                              hipStream_t stream) {
    const float* node_feats = (const float*)d_in[0];
    const float* ef0 = (const float*)d_in[1];
    const float* ef1 = (const float*)d_in[2];
    const int* src = (const int*)d_in[3];
    const int* dst = (const int*)d_in[4];
    const float* We0 = (const float*)d_in[5];
    const float* be0 = (const float*)d_in[6];
    const float* We1 = (const float*)d_in[7];
    const float* be1 = (const float*)d_in[8];
    const float* W1 = (const float*)d_in[9];
    const float* b1 = (const float*)d_in[10];
    const float* W2 = (const float*)d_in[11];
    const float* b2 = (const float*)d_in[12];
    const float* gamma = (const float*)d_in[13];
    const float* beta = (const float*)d_in[14];

    float* out = (float*)d_out;
    float* stats = (float*)d_ws;                       // NSLAB * 2*EMB floats
    float* scaleshift = stats + NSLAB * 2 * EMB;       // 2*EMB floats

    // zero agg accumulator (d_out) and stats slabs
    hipMemsetAsync(d_out, 0, (size_t)N_NODES * EMB * sizeof(float), stream);
    hipMemsetAsync(d_ws, 0, (size_t)(NSLAB * 2 * EMB + 2 * EMB) * sizeof(float), stream);

    edge_scatter_kernel<<<N_EDGES / 2, 256, 0, stream>>>(
        node_feats, ef0, ef1, src, dst, We0, be0, We1, be1, out);

    mlp_kernel<<<N_NODES / BM, 256, 0, stream>>>(out, W1, b1, W2, b2, stats);

    bn_finalize_kernel<<<1, 128, 0, stream>>>(stats, gamma, beta, scaleshift);

    bn_apply_kernel<<<2048, 256, 0, stream>>>(out, scaleshift);
}

// Round 2
// 825.233 us; speedup vs baseline: 1.8074x; 1.8074x over previous
//
#include <hip/hip_runtime.h>

#define N_NODES 100000
#define N_EDGES 1600000
#define EMB 128
#define BM 16
#define NSLAB 64
#define BN_EPS 1e-5f

#define SCAN_BLK 512
#define NB_SCAN ((N_NODES + SCAN_BLK - 1) / SCAN_BLK)   // 196
#define NPAD 100352                                     // NB_SCAN*SCAN_BLK

// =================== sorted-gather path ===================

// ---- hist: counts[dst[e]]++ ----
__global__ __launch_bounds__(256) void hist_kernel(
    const int* __restrict__ dst, int* __restrict__ counts)
{
    int e = blockIdx.x * 256 + threadIdx.x;
    if (e < N_EDGES) atomicAdd(&counts[dst[e]], 1);
}

// ---- scan A: per-block sums ----
__global__ __launch_bounds__(SCAN_BLK) void scan_blocksum_kernel(
    const int* __restrict__ counts, int* __restrict__ blockSums)
{
    __shared__ int red[SCAN_BLK];
    int t = threadIdx.x;
    int i = blockIdx.x * SCAN_BLK + t;
    red[t] = (i < N_NODES) ? counts[i] : 0;
    __syncthreads();
    for (int s = SCAN_BLK / 2; s > 0; s >>= 1) {
        if (t < s) red[t] += red[t + s];
        __syncthreads();
    }
    if (t == 0) blockSums[blockIdx.x] = red[0];
}

// ---- scan B: exclusive scan of block sums (single block) ----
__global__ __launch_bounds__(256) void scan_blockoffsets_kernel(int* __restrict__ blockSums)
{
    __shared__ int s[256];
    int t = threadIdx.x;
    int orig = (t < NB_SCAN) ? blockSums[t] : 0;
    s[t] = orig;
    __syncthreads();
    for (int off = 1; off < 256; off <<= 1) {
        int v = (t >= off) ? s[t - off] : 0;
        __syncthreads();
        s[t] += v;
        __syncthreads();
    }
    if (t < NB_SCAN) blockSums[t] = s[t] - orig;  // exclusive
}

// ---- scan C: per-element exclusive offsets + cursor ----
__global__ __launch_bounds__(SCAN_BLK) void scan_final_kernel(
    const int* __restrict__ counts, const int* __restrict__ blockSums,
    int* __restrict__ offsets, int* __restrict__ cursor)
{
    __shared__ int s[SCAN_BLK];
    int t = threadIdx.x;
    int i = blockIdx.x * SCAN_BLK + t;
    int orig = (i < N_NODES) ? counts[i] : 0;
    s[t] = orig;
    __syncthreads();
    for (int off = 1; off < SCAN_BLK; off <<= 1) {
        int v = (t >= off) ? s[t - off] : 0;
        __syncthreads();
        s[t] += v;
        __syncthreads();
    }
    int excl = s[t] - orig + blockSums[blockIdx.x];
    if (i < N_NODES) { offsets[i] = excl; cursor[i] = excl; }
    if (i == N_NODES) offsets[N_NODES] = N_EDGES;
}

// ---- scatter: sorted[pos] = {src, edge_id} ----
__global__ __launch_bounds__(256) void scatter_kernel(
    const int* __restrict__ src, const int* __restrict__ dst,
    int* __restrict__ cursor, int2* __restrict__ sorted)
{
    int e = blockIdx.x * 256 + threadIdx.x;
    if (e >= N_EDGES) return;
    int t = dst[e];
    int pos = atomicAdd(&cursor[t], 1);
    sorted[pos] = make_int2(src[e], e);
}

// ---- gather-reduce: one wave per node, lane owns 2 dims ----
__global__ __launch_bounds__(256) void gather_reduce_kernel(
    const float* __restrict__ node_feats,
    const float* __restrict__ ef0, const float* __restrict__ ef1,
    const int2* __restrict__ sorted, const int* __restrict__ offsets,
    const float* __restrict__ We0, const float* __restrict__ be0,
    const float* __restrict__ We1, const float* __restrict__ be1,
    float* __restrict__ agg)
{
    int wave = threadIdx.x >> 6;
    int lane = threadIdx.x & 63;
    int n = blockIdx.x * 4 + wave;
    if (n >= N_NODES) return;

    // per-lane weights (dims 2*lane, 2*lane+1) in registers
    float2 w0[6], w1[3];
#pragma unroll
    for (int k = 0; k < 6; ++k) w0[k] = ((const float2*)We0)[k * 64 + lane];
#pragma unroll
    for (int k = 0; k < 3; ++k) w1[k] = ((const float2*)We1)[k * 64 + lane];
    float2 bias;
    {
        float2 a = ((const float2*)be0)[lane];
        float2 b = ((const float2*)be1)[lane];
        bias.x = a.x + b.x; bias.y = a.y + b.y;
    }

    int beg = offsets[n];
    int end = offsets[n + 1];
    float2 acc = make_float2(0.f, 0.f);

    for (int i = beg; i < end; ++i) {
        int2 se = sorted[i];
        // lanes 0..5 hold ef0[k], lanes 6..8 hold ef1[k-6]
        float f = 0.f;
        if (lane < 6)      f = ef0[(long)se.y * 6 + lane];
        else if (lane < 9) f = ef1[(long)se.y * 3 + (lane - 6)];

        float2 emb = bias;
#pragma unroll
        for (int k = 0; k < 6; ++k) {
            float fk = __shfl(f, k);
            emb.x = fmaf(fk, w0[k].x, emb.x);
            emb.y = fmaf(fk, w0[k].y, emb.y);
        }
#pragma unroll
        for (int k = 0; k < 3; ++k) {
            float fk = __shfl(f, 6 + k);
            emb.x = fmaf(fk, w1[k].x, emb.x);
            emb.y = fmaf(fk, w1[k].y, emb.y);
        }
        float2 nf = ((const float2*)node_feats)[(long)se.x * 64 + lane];
        acc.x += nf.x + emb.x;
        acc.y += nf.y + emb.y;
    }
    ((float2*)agg)[(long)n * 64 + lane] = acc;
}

// =================== fallback atomic path (small ws) ===================
__global__ __launch_bounds__(256) void edge_scatter_kernel(
    const float* __restrict__ node_feats,
    const float* __restrict__ ef0,
    const float* __restrict__ ef1,
    const int* __restrict__ src,
    const int* __restrict__ dst,
    const float* __restrict__ We0, const float* __restrict__ be0,
    const float* __restrict__ We1, const float* __restrict__ be1,
    float* __restrict__ agg)
{
    __shared__ float wS[10 * EMB];
    int tid = threadIdx.x;
    for (int i = tid; i < 6 * EMB; i += 256) wS[i] = We0[i];
    for (int i = tid; i < 3 * EMB; i += 256) wS[6 * EMB + i] = We1[i];
    if (tid < EMB) wS[9 * EMB + tid] = be0[tid] + be1[tid];
    __syncthreads();

    int e = blockIdx.x * 2 + (tid >> 7);
    if (e >= N_EDGES) return;
    int d = tid & 127;
    int s = src[e];
    int t = dst[e];
    const float* f0 = ef0 + (long)e * 6;
    const float* f1 = ef1 + (long)e * 3;

    float emb = wS[9 * EMB + d];
#pragma unroll
    for (int k = 0; k < 6; ++k) emb = fmaf(f0[k], wS[k * EMB + d], emb);
#pragma unroll
    for (int k = 0; k < 3; ++k) emb = fmaf(f1[k], wS[6 * EMB + k * EMB + d], emb);

    float val = node_feats[(long)s * EMB + d] + emb;
    atomicAdd(&agg[(long)t * EMB + d], val);
}

// =================== MLP + BN (unchanged from R1) ===================
__global__ __launch_bounds__(256) void mlp_kernel(
    float* __restrict__ h,
    const float* __restrict__ W1, const float* __restrict__ b1,
    const float* __restrict__ W2, const float* __restrict__ b2,
    float* __restrict__ stats)
{
    __shared__ float aggS[BM][EMB];
    __shared__ float h1S[BM][2 * EMB];
    __shared__ float sredS[256];
    __shared__ float s2redS[256];

    int tid = threadIdx.x;
    long base = (long)blockIdx.x * BM;

    for (int i = tid; i < BM * EMB; i += 256)
        aggS[i >> 7][i & 127] = h[base * EMB + i];
    __syncthreads();

    {
        float acc[BM];
        float bias = b1[tid];
#pragma unroll
        for (int r = 0; r < BM; ++r) acc[r] = bias;
        for (int k = 0; k < EMB; ++k) {
            float w = W1[k * (2 * EMB) + tid];
#pragma unroll
            for (int r = 0; r < BM; ++r) acc[r] = fmaf(aggS[r][k], w, acc[r]);
        }
#pragma unroll
        for (int r = 0; r < BM; ++r) h1S[r][tid] = fmaxf(acc[r], 0.0f);
    }
    __syncthreads();

    {
        int c = tid & 127;
        int half = tid >> 7;
        float acc[8];
        float bias = b2[c];
#pragma unroll
        for (int r = 0; r < 8; ++r) acc[r] = bias;
        for (int k = 0; k < 2 * EMB; ++k) {
            float w = W2[k * EMB + c];
#pragma unroll
            for (int r = 0; r < 8; ++r) acc[r] = fmaf(h1S[half * 8 + r][k], w, acc[r]);
        }
        float s = 0.f, s2 = 0.f;
#pragma unroll
        for (int r = 0; r < 8; ++r) {
            h[(base + half * 8 + r) * EMB + c] = acc[r];
            s += acc[r];
            s2 = fmaf(acc[r], acc[r], s2);
        }
        sredS[tid] = s;
        s2redS[tid] = s2;
    }
    __syncthreads();
    if (tid < 128) {
        float s = sredS[tid] + sredS[tid + 128];
        float s2 = s2redS[tid] + s2redS[tid + 128];
        float* slab = stats + (blockIdx.x & (NSLAB - 1)) * (2 * EMB);
        atomicAdd(&slab[tid], s);
        atomicAdd(&slab[EMB + tid], s2);
    }
}

__global__ __launch_bounds__(128) void bn_finalize_kernel(
    const float* __restrict__ stats,
    const float* __restrict__ gamma, const float* __restrict__ beta,
    float* __restrict__ scaleshift)
{
    int c = threadIdx.x;
    float s = 0.f, s2 = 0.f;
    for (int b = 0; b < NSLAB; ++b) {
        s += stats[b * (2 * EMB) + c];
        s2 += stats[b * (2 * EMB) + EMB + c];
    }
    float mean = s / (float)N_NODES;
    float var = s2 / (float)N_NODES - mean * mean;
    float sc = gamma[c] * rsqrtf(var + BN_EPS);
    scaleshift[c] = sc;
    scaleshift[EMB + c] = beta[c] - mean * sc;
}

__global__ __launch_bounds__(256) void bn_apply_kernel(
    float* __restrict__ h, const float* __restrict__ scaleshift)
{
    __shared__ float scS[EMB], shS[EMB];
    if (threadIdx.x < EMB) {
        scS[threadIdx.x] = scaleshift[threadIdx.x];
        shS[threadIdx.x] = scaleshift[EMB + threadIdx.x];
    }
    __syncthreads();
    long total = (long)N_NODES * EMB / 4;
    long stride = (long)gridDim.x * blockDim.x;
    for (long i = (long)blockIdx.x * blockDim.x + threadIdx.x; i < total; i += stride) {
        float4 v = ((float4*)h)[i];
        int c = (int)((i * 4) & 127);
        v.x = fmaf(v.x, scS[c + 0], shS[c + 0]);
        v.y = fmaf(v.y, scS[c + 1], shS[c + 1]);
        v.z = fmaf(v.z, scS[c + 2], shS[c + 2]);
        v.w = fmaf(v.w, scS[c + 3], shS[c + 3]);
        ((float4*)h)[i] = v;
    }
}

extern "C" void kernel_launch(void* const* d_in, const int* in_sizes, int n_in,
                              void* d_out, int out_size, void* d_ws, size_t ws_size,
                              hipStream_t stream) {
    const float* node_feats = (const float*)d_in[0];
    const float* ef0 = (const float*)d_in[1];
    const float* ef1 = (const float*)d_in[2];
    const int* src = (const int*)d_in[3];
    const int* dst = (const int*)d_in[4];
    const float* We0 = (const float*)d_in[5];
    const float* be0 = (const float*)d_in[6];
    const float* We1 = (const float*)d_in[7];
    const float* be1 = (const float*)d_in[8];
    const float* W1 = (const float*)d_in[9];
    const float* b1 = (const float*)d_in[10];
    const float* W2 = (const float*)d_in[11];
    const float* b2 = (const float*)d_in[12];
    const float* gamma = (const float*)d_in[13];
    const float* beta = (const float*)d_in[14];

    float* out = (float*)d_out;

    // ws layout: stats | scaleshift | counts | offsets | cursor | blockSums | sorted
    float* stats = (float*)d_ws;                         // NSLAB*2*EMB floats (64 KB)
    float* scaleshift = stats + NSLAB * 2 * EMB;         // 256 floats
    int* counts = (int*)(scaleshift + 256);              // NPAD ints
    int* offsets = counts + NPAD;                        // NPAD ints (uses N_NODES+1)
    int* cursor = offsets + NPAD;                        // NPAD ints
    int* blockSums = cursor + NPAD;                      // 256 ints
    int2* sorted = (int2*)(blockSums + 256);             // N_EDGES int2 (12.8 MB)
    size_t needed = (size_t)((char*)(sorted + N_EDGES) - (char*)d_ws);

    hipMemsetAsync(stats, 0, (size_t)NSLAB * 2 * EMB * sizeof(float), stream);

    if (ws_size >= needed) {
        hipMemsetAsync(counts, 0, (size_t)N_NODES * sizeof(int), stream);
        hist_kernel<<<(N_EDGES + 255) / 256, 256, 0, stream>>>(dst, counts);
        scan_blocksum_kernel<<<NB_SCAN, SCAN_BLK, 0, stream>>>(counts, blockSums);
        scan_blockoffsets_kernel<<<1, 256, 0, stream>>>(blockSums);
        scan_final_kernel<<<NB_SCAN, SCAN_BLK, 0, stream>>>(counts, blockSums, offsets, cursor);
        scatter_kernel<<<(N_EDGES + 255) / 256, 256, 0, stream>>>(src, dst, cursor, sorted);
        gather_reduce_kernel<<<(N_NODES + 3) / 4, 256, 0, stream>>>(
            node_feats, ef0, ef1, sorted, offsets, We0, be0, We1, be1, out);
    } else {
        // fallback: atomic scatter path
        hipMemsetAsync(d_out, 0, (size_t)N_NODES * EMB * sizeof(float), stream);
        edge_scatter_kernel<<<N_EDGES / 2, 256, 0, stream>>>(
            node_feats, ef0, ef1, src, dst, We0, be0, We1, be1, out);
    }

    mlp_kernel<<<N_NODES / BM, 256, 0, stream>>>(out, W1, b1, W2, b2, stats);
    bn_finalize_kernel<<<1, 128, 0, stream>>>(stats, gamma, beta, scaleshift);
    bn_apply_kernel<<<2048, 256, 0, stream>>>(out, scaleshift);
}

// Round 3
// 570.801 us; speedup vs baseline: 2.6131x; 1.4457x over previous
//
#include <hip/hip_runtime.h>

#define N_NODES 100000
#define N_EDGES 1600000
#define EMB 128
#define BM 16
#define NSLAB 64
#define BN_EPS 1e-5f

#define SCAN_BLK 512
#define NB_SCAN ((N_NODES + SCAN_BLK - 1) / SCAN_BLK)   // 196
#define NPAD (NB_SCAN * SCAN_BLK)                       // 100352
#define RECW 10

// =================== sort machinery ===================

__global__ __launch_bounds__(256) void hist_kernel(
    const int* __restrict__ dst, int* __restrict__ counts)
{
    int e = blockIdx.x * 256 + threadIdx.x;
    if (e < N_EDGES) atomicAdd(&counts[dst[e]], 1);
}

__global__ __launch_bounds__(SCAN_BLK) void scan_blocksum_kernel(
    const int* __restrict__ counts, int* __restrict__ blockSums)
{
    __shared__ int red[SCAN_BLK];
    int t = threadIdx.x;
    int i = blockIdx.x * SCAN_BLK + t;
    red[t] = (i < N_NODES) ? counts[i] : 0;
    __syncthreads();
    for (int s = SCAN_BLK / 2; s > 0; s >>= 1) {
        if (t < s) red[t] += red[t + s];
        __syncthreads();
    }
    if (t == 0) blockSums[blockIdx.x] = red[0];
}

__global__ __launch_bounds__(256) void scan_blockoffsets_kernel(int* __restrict__ blockSums)
{
    __shared__ int s[256];
    int t = threadIdx.x;
    int orig = (t < NB_SCAN) ? blockSums[t] : 0;
    s[t] = orig;
    __syncthreads();
    for (int off = 1; off < 256; off <<= 1) {
        int v = (t >= off) ? s[t - off] : 0;
        __syncthreads();
        s[t] += v;
        __syncthreads();
    }
    if (t < NB_SCAN) blockSums[t] = s[t] - orig;  // exclusive
}

__global__ __launch_bounds__(SCAN_BLK) void scan_final_kernel(
    const int* __restrict__ counts, const int* __restrict__ blockSums,
    int* __restrict__ offsets, int* __restrict__ cursor)
{
    __shared__ int s[SCAN_BLK];
    int t = threadIdx.x;
    int i = blockIdx.x * SCAN_BLK + t;
    int orig = (i < N_NODES) ? counts[i] : 0;
    s[t] = orig;
    __syncthreads();
    for (int off = 1; off < SCAN_BLK; off <<= 1) {
        int v = (t >= off) ? s[t - off] : 0;
        __syncthreads();
        s[t] += v;
        __syncthreads();
    }
    int excl = s[t] - orig + blockSums[blockIdx.x];
    if (i < N_NODES) { offsets[i] = excl; cursor[i] = excl; }
    if (i == N_NODES) offsets[N_NODES] = N_EDGES;
}

// =================== NEW path: fat records ===================
// rec[pos] = { src_bits, f0[0..5], f1[0..2] } (10 floats, 40 B)
__global__ __launch_bounds__(256) void scatter_rec_kernel(
    const int* __restrict__ src, const int* __restrict__ dst,
    const float* __restrict__ ef0, const float* __restrict__ ef1,
    int* __restrict__ cursor, float* __restrict__ recF)
{
    int e = blockIdx.x * 256 + threadIdx.x;
    if (e >= N_EDGES) return;
    int pos = atomicAdd(&cursor[dst[e]], 1);
    float r[RECW];
    r[0] = __int_as_float(src[e]);
    const float2* f0 = (const float2*)(ef0 + (long)e * 6);
    float2 a = f0[0], b = f0[1], c = f0[2];
    r[1] = a.x; r[2] = a.y; r[3] = b.x; r[4] = b.y; r[5] = c.x; r[6] = c.y;
    r[7] = ef1[(long)e * 3 + 0];
    r[8] = ef1[(long)e * 3 + 1];
    r[9] = ef1[(long)e * 3 + 2];
    float* out = recF + (long)pos * RECW;
#pragma unroll
    for (int j = 0; j < RECW; ++j) out[j] = r[j];
}

// one wave per node; chunk of 6 records = 60-lane coalesced load;
// 6 independent node_feats row loads per chunk; features folded per node.
__global__ __launch_bounds__(256) void gather_rec_kernel(
    const float* __restrict__ node_feats,
    const float* __restrict__ recF, const int* __restrict__ offsets,
    const float* __restrict__ We0, const float* __restrict__ be0,
    const float* __restrict__ We1, const float* __restrict__ be1,
    float* __restrict__ agg)
{
    int wave = threadIdx.x >> 6;
    int lane = threadIdx.x & 63;
    int n = blockIdx.x * 4 + wave;
    if (n >= N_NODES) return;

    float2 w[9];
#pragma unroll
    for (int k = 0; k < 6; ++k) w[k] = ((const float2*)We0)[k * 64 + lane];
#pragma unroll
    for (int k = 0; k < 3; ++k) w[6 + k] = ((const float2*)We1)[k * 64 + lane];
    float2 bias;
    {
        float2 a = ((const float2*)be0)[lane];
        float2 b = ((const float2*)be1)[lane];
        bias.x = a.x + b.x; bias.y = a.y + b.y;
    }

    int beg = offsets[n];
    int end = offsets[n + 1];
    int col = lane % 10;          // record column owned by this lane (lanes<60)
    float colsum = 0.f;
    float2 acc = make_float2(0.f, 0.f);
    const float2* nf2 = (const float2*)node_feats;

    for (int base = beg; base < end; base += 6) {
        int m = end - base; if (m > 6) m = 6;
        float v = 0.f;
        if (lane < m * 10) v = recF[(long)base * RECW + lane];
        if (col != 0) colsum += v;   // v==0 for idle lanes
#pragma unroll 6
        for (int j = 0; j < 6; ++j) {
            if (j >= m) break;
            int s = __float_as_int(__shfl(v, j * 10));
            float2 nf = nf2[(long)s * 64 + lane];
            acc.x += nf.x;
            acc.y += nf.y;
        }
    }

    // reduce 6 row-partials (lanes 0..59, row=lane/10) onto lanes 0..9
    float s1 = colsum + __shfl(colsum, lane + 30);                 // lanes 0-29 valid
    float tot = s1 + __shfl(s1, lane + 10) + __shfl(s1, lane + 20); // lanes 0-9 valid

    float deg = (float)(end - beg);
    float2 emb = make_float2(deg * bias.x, deg * bias.y);
#pragma unroll
    for (int k = 0; k < 9; ++k) {
        float fk = __shfl(tot, k + 1);   // column k+1 holds feature k sum
        emb.x = fmaf(fk, w[k].x, emb.x);
        emb.y = fmaf(fk, w[k].y, emb.y);
    }
    acc.x += emb.x;
    acc.y += emb.y;
    ((float2*)agg)[(long)n * 64 + lane] = acc;
}

// =================== MIDDLE tier (R2 int2 path) ===================
__global__ __launch_bounds__(256) void scatter_kernel(
    const int* __restrict__ src, const int* __restrict__ dst,
    int* __restrict__ cursor, int2* __restrict__ sorted)
{
    int e = blockIdx.x * 256 + threadIdx.x;
    if (e >= N_EDGES) return;
    int t = dst[e];
    int pos = atomicAdd(&cursor[t], 1);
    sorted[pos] = make_int2(src[e], e);
}

__global__ __launch_bounds__(256) void gather_reduce_kernel(
    const float* __restrict__ node_feats,
    const float* __restrict__ ef0, const float* __restrict__ ef1,
    const int2* __restrict__ sorted, const int* __restrict__ offsets,
    const float* __restrict__ We0, const float* __restrict__ be0,
    const float* __restrict__ We1, const float* __restrict__ be1,
    float* __restrict__ agg)
{
    int wave = threadIdx.x >> 6;
    int lane = threadIdx.x & 63;
    int n = blockIdx.x * 4 + wave;
    if (n >= N_NODES) return;

    float2 w0[6], w1[3];
#pragma unroll
    for (int k = 0; k < 6; ++k) w0[k] = ((const float2*)We0)[k * 64 + lane];
#pragma unroll
    for (int k = 0; k < 3; ++k) w1[k] = ((const float2*)We1)[k * 64 + lane];
    float2 bias;
    {
        float2 a = ((const float2*)be0)[lane];
        float2 b = ((const float2*)be1)[lane];
        bias.x = a.x + b.x; bias.y = a.y + b.y;
    }

    int beg = offsets[n];
    int end = offsets[n + 1];
    float2 acc = make_float2(0.f, 0.f);

    for (int i = beg; i < end; ++i) {
        int2 se = sorted[i];
        float f = 0.f;
        if (lane < 6)      f = ef0[(long)se.y * 6 + lane];
        else if (lane < 9) f = ef1[(long)se.y * 3 + (lane - 6)];

        float2 emb = bias;
#pragma unroll
        for (int k = 0; k < 6; ++k) {
            float fk = __shfl(f, k);
            emb.x = fmaf(fk, w0[k].x, emb.x);
            emb.y = fmaf(fk, w0[k].y, emb.y);
        }
#pragma unroll
        for (int k = 0; k < 3; ++k) {
            float fk = __shfl(f, 6 + k);
            emb.x = fmaf(fk, w1[k].x, emb.x);
            emb.y = fmaf(fk, w1[k].y, emb.y);
        }
        float2 nf = ((const float2*)node_feats)[(long)se.x * 64 + lane];
        acc.x += nf.x + emb.x;
        acc.y += nf.y + emb.y;
    }
    ((float2*)agg)[(long)n * 64 + lane] = acc;
}

// =================== LAST resort: atomic path ===================
__global__ __launch_bounds__(256) void edge_scatter_kernel(
    const float* __restrict__ node_feats,
    const float* __restrict__ ef0,
    const float* __restrict__ ef1,
    const int* __restrict__ src,
    const int* __restrict__ dst,
    const float* __restrict__ We0, const float* __restrict__ be0,
    const float* __restrict__ We1, const float* __restrict__ be1,
    float* __restrict__ agg)
{
    __shared__ float wS[10 * EMB];
    int tid = threadIdx.x;
    for (int i = tid; i < 6 * EMB; i += 256) wS[i] = We0[i];
    for (int i = tid; i < 3 * EMB; i += 256) wS[6 * EMB + i] = We1[i];
    if (tid < EMB) wS[9 * EMB + tid] = be0[tid] + be1[tid];
    __syncthreads();

    int e = blockIdx.x * 2 + (tid >> 7);
    if (e >= N_EDGES) return;
    int d = tid & 127;
    int s = src[e];
    int t = dst[e];
    const float* f0 = ef0 + (long)e * 6;
    const float* f1 = ef1 + (long)e * 3;

    float emb = wS[9 * EMB + d];
#pragma unroll
    for (int k = 0; k < 6; ++k) emb = fmaf(f0[k], wS[k * EMB + d], emb);
#pragma unroll
    for (int k = 0; k < 3; ++k) emb = fmaf(f1[k], wS[6 * EMB + k * EMB + d], emb);

    float val = node_feats[(long)s * EMB + d] + emb;
    atomicAdd(&agg[(long)t * EMB + d], val);
}

// =================== MLP + BN ===================
__global__ __launch_bounds__(256) void mlp_kernel(
    float* __restrict__ h,
    const float* __restrict__ W1, const float* __restrict__ b1,
    const float* __restrict__ W2, const float* __restrict__ b2,
    float* __restrict__ stats)
{
    __shared__ float aggS[BM][EMB];
    __shared__ float h1S[BM][2 * EMB];
    __shared__ float sredS[256];
    __shared__ float s2redS[256];

    int tid = threadIdx.x;
    long base = (long)blockIdx.x * BM;

    for (int i = tid; i < BM * EMB; i += 256)
        aggS[i >> 7][i & 127] = h[base * EMB + i];
    __syncthreads();

    {
        float acc[BM];
        float bias = b1[tid];
#pragma unroll
        for (int r = 0; r < BM; ++r) acc[r] = bias;
        for (int k = 0; k < EMB; ++k) {
            float w = W1[k * (2 * EMB) + tid];
#pragma unroll
            for (int r = 0; r < BM; ++r) acc[r] = fmaf(aggS[r][k], w, acc[r]);
        }
#pragma unroll
        for (int r = 0; r < BM; ++r) h1S[r][tid] = fmaxf(acc[r], 0.0f);
    }
    __syncthreads();

    {
        int c = tid & 127;
        int half = tid >> 7;
        float acc[8];
        float bias = b2[c];
#pragma unroll
        for (int r = 0; r < 8; ++r) acc[r] = bias;
        for (int k = 0; k < 2 * EMB; ++k) {
            float w = W2[k * EMB + c];
#pragma unroll
            for (int r = 0; r < 8; ++r) acc[r] = fmaf(h1S[half * 8 + r][k], w, acc[r]);
        }
        float s = 0.f, s2 = 0.f;
#pragma unroll
        for (int r = 0; r < 8; ++r) {
            h[(base + half * 8 + r) * EMB + c] = acc[r];
            s += acc[r];
            s2 = fmaf(acc[r], acc[r], s2);
        }
        sredS[tid] = s;
        s2redS[tid] = s2;
    }
    __syncthreads();
    if (tid < 128) {
        float s = sredS[tid] + sredS[tid + 128];
        float s2 = s2redS[tid] + s2redS[tid + 128];
        float* slab = stats + (blockIdx.x & (NSLAB - 1)) * (2 * EMB);
        atomicAdd(&slab[tid], s);
        atomicAdd(&slab[EMB + tid], s2);
    }
}

__global__ __launch_bounds__(128) void bn_finalize_kernel(
    const float* __restrict__ stats,
    const float* __restrict__ gamma, const float* __restrict__ beta,
    float* __restrict__ scaleshift)
{
    int c = threadIdx.x;
    float s = 0.f, s2 = 0.f;
    for (int b = 0; b < NSLAB; ++b) {
        s += stats[b * (2 * EMB) + c];
        s2 += stats[b * (2 * EMB) + EMB + c];
    }
    float mean = s / (float)N_NODES;
    float var = s2 / (float)N_NODES - mean * mean;
    float sc = gamma[c] * rsqrtf(var + BN_EPS);
    scaleshift[c] = sc;
    scaleshift[EMB + c] = beta[c] - mean * sc;
}

__global__ __launch_bounds__(256) void bn_apply_kernel(
    float* __restrict__ h, const float* __restrict__ scaleshift)
{
    __shared__ float scS[EMB], shS[EMB];
    if (threadIdx.x < EMB) {
        scS[threadIdx.x] = scaleshift[threadIdx.x];
        shS[threadIdx.x] = scaleshift[EMB + threadIdx.x];
    }
    __syncthreads();
    long total = (long)N_NODES * EMB / 4;
    long stride = (long)gridDim.x * blockDim.x;
    for (long i = (long)blockIdx.x * blockDim.x + threadIdx.x; i < total; i += stride) {
        float4 v = ((float4*)h)[i];
        int c = (int)((i * 4) & 127);
        v.x = fmaf(v.x, scS[c + 0], shS[c + 0]);
        v.y = fmaf(v.y, scS[c + 1], shS[c + 1]);
        v.z = fmaf(v.z, scS[c + 2], shS[c + 2]);
        v.w = fmaf(v.w, scS[c + 3], shS[c + 3]);
        ((float4*)h)[i] = v;
    }
}

extern "C" void kernel_launch(void* const* d_in, const int* in_sizes, int n_in,
                              void* d_out, int out_size, void* d_ws, size_t ws_size,
                              hipStream_t stream) {
    const float* node_feats = (const float*)d_in[0];
    const float* ef0 = (const float*)d_in[1];
    const float* ef1 = (const float*)d_in[2];
    const int* src = (const int*)d_in[3];
    const int* dst = (const int*)d_in[4];
    const float* We0 = (const float*)d_in[5];
    const float* be0 = (const float*)d_in[6];
    const float* We1 = (const float*)d_in[7];
    const float* be1 = (const float*)d_in[8];
    const float* W1 = (const float*)d_in[9];
    const float* b1 = (const float*)d_in[10];
    const float* W2 = (const float*)d_in[11];
    const float* b2 = (const float*)d_in[12];
    const float* gamma = (const float*)d_in[13];
    const float* beta = (const float*)d_in[14];

    float* out = (float*)d_out;

    // ws layout: stats | scaleshift | counts | offsets | cursor | blockSums | payload
    float* stats = (float*)d_ws;                         // NSLAB*2*EMB floats
    float* scaleshift = stats + NSLAB * 2 * EMB;         // 256 floats
    int* counts = (int*)(scaleshift + 256);              // NPAD ints
    int* offsets = counts + NPAD;                        // NPAD ints
    int* cursor = offsets + NPAD;                        // NPAD ints
    int* blockSums = cursor + NPAD;                      // 256 ints
    float* recF = (float*)(blockSums + 256);             // E*10 floats (64 MB)
    int2* sorted = (int2*)(blockSums + 256);             // E int2 (12.8 MB)
    size_t needRec = (size_t)((char*)(recF + (size_t)N_EDGES * RECW) - (char*)d_ws);
    size_t needSorted = (size_t)((char*)(sorted + N_EDGES) - (char*)d_ws);

    hipMemsetAsync(stats, 0, (size_t)NSLAB * 2 * EMB * sizeof(float), stream);

    if (ws_size >= needSorted) {
        hipMemsetAsync(counts, 0, (size_t)N_NODES * sizeof(int), stream);
        hist_kernel<<<(N_EDGES + 255) / 256, 256, 0, stream>>>(dst, counts);
        scan_blocksum_kernel<<<NB_SCAN, SCAN_BLK, 0, stream>>>(counts, blockSums);
        scan_blockoffsets_kernel<<<1, 256, 0, stream>>>(blockSums);
        scan_final_kernel<<<NB_SCAN, SCAN_BLK, 0, stream>>>(counts, blockSums, offsets, cursor);
        if (ws_size >= needRec) {
            scatter_rec_kernel<<<(N_EDGES + 255) / 256, 256, 0, stream>>>(
                src, dst, ef0, ef1, cursor, recF);
            gather_rec_kernel<<<(N_NODES + 3) / 4, 256, 0, stream>>>(
                node_feats, recF, offsets, We0, be0, We1, be1, out);
        } else {
            scatter_kernel<<<(N_EDGES + 255) / 256, 256, 0, stream>>>(src, dst, cursor, sorted);
            gather_reduce_kernel<<<(N_NODES + 3) / 4, 256, 0, stream>>>(
                node_feats, ef0, ef1, sorted, offsets, We0, be0, We1, be1, out);
        }
    } else {
        hipMemsetAsync(d_out, 0, (size_t)N_NODES * EMB * sizeof(float), stream);
        edge_scatter_kernel<<<N_EDGES / 2, 256, 0, stream>>>(
            node_feats, ef0, ef1, src, dst, We0, be0, We1, be1, out);
    }

    mlp_kernel<<<N_NODES / BM, 256, 0, stream>>>(out, W1, b1, W2, b2, stats);
    bn_finalize_kernel<<<1, 128, 0, stream>>>(stats, gamma, beta, scaleshift);
    bn_apply_kernel<<<2048, 256, 0, stream>>>(out, scaleshift);
}

// Round 4
// 375.783 us; speedup vs baseline: 3.9692x; 1.5190x over previous
//
#include <hip/hip_runtime.h>

#define N_NODES 100000
#define N_EDGES 1600000
#define EMB 128
#define BM 16
#define NSLAB 64
#define BN_EPS 1e-5f

#define SCAN_BLK 512
#define NB_SCAN ((N_NODES + SCAN_BLK - 1) / SCAN_BLK)   // 196
#define NPAD (NB_SCAN * SCAN_BLK)                       // 100352
#define RECW 10

typedef short short8 __attribute__((ext_vector_type(8)));
typedef float floatx4 __attribute__((ext_vector_type(4)));

__device__ __forceinline__ ushort f2bf(float x) {
    unsigned u = __float_as_uint(x);
    u += 0x7fffu + ((u >> 16) & 1u);   // RNE
    return (ushort)(u >> 16);
}

// =================== sort machinery ===================

__global__ __launch_bounds__(256) void hist_kernel(
    const int* __restrict__ dst, int* __restrict__ counts)
{
    int e = blockIdx.x * 256 + threadIdx.x;
    if (e < N_EDGES) atomicAdd(&counts[dst[e]], 1);
}

__global__ __launch_bounds__(SCAN_BLK) void scan_blocksum_kernel(
    const int* __restrict__ counts, int* __restrict__ blockSums)
{
    __shared__ int red[SCAN_BLK];
    int t = threadIdx.x;
    int i = blockIdx.x * SCAN_BLK + t;
    red[t] = (i < N_NODES) ? counts[i] : 0;
    __syncthreads();
    for (int s = SCAN_BLK / 2; s > 0; s >>= 1) {
        if (t < s) red[t] += red[t + s];
        __syncthreads();
    }
    if (t == 0) blockSums[blockIdx.x] = red[0];
}

__global__ __launch_bounds__(256) void scan_blockoffsets_kernel(int* __restrict__ blockSums)
{
    __shared__ int s[256];
    int t = threadIdx.x;
    int orig = (t < NB_SCAN) ? blockSums[t] : 0;
    s[t] = orig;
    __syncthreads();
    for (int off = 1; off < 256; off <<= 1) {
        int v = (t >= off) ? s[t - off] : 0;
        __syncthreads();
        s[t] += v;
        __syncthreads();
    }
    if (t < NB_SCAN) blockSums[t] = s[t] - orig;  // exclusive
}

__global__ __launch_bounds__(SCAN_BLK) void scan_final_kernel(
    const int* __restrict__ counts, const int* __restrict__ blockSums,
    int* __restrict__ offsets, int* __restrict__ cursor)
{
    __shared__ int s[SCAN_BLK];
    int t = threadIdx.x;
    int i = blockIdx.x * SCAN_BLK + t;
    int orig = (i < N_NODES) ? counts[i] : 0;
    s[t] = orig;
    __syncthreads();
    for (int off = 1; off < SCAN_BLK; off <<= 1) {
        int v = (t >= off) ? s[t - off] : 0;
        __syncthreads();
        s[t] += v;
        __syncthreads();
    }
    int excl = s[t] - orig + blockSums[blockIdx.x];
    if (i < N_NODES) { offsets[i] = excl; cursor[i] = excl; }
    if (i == N_NODES) offsets[N_NODES] = N_EDGES;
}

// =================== fat-record path ===================
__global__ __launch_bounds__(256) void scatter_rec_kernel(
    const int* __restrict__ src, const int* __restrict__ dst,
    const float* __restrict__ ef0, const float* __restrict__ ef1,
    int* __restrict__ cursor, float* __restrict__ recF)
{
    int e = blockIdx.x * 256 + threadIdx.x;
    if (e >= N_EDGES) return;
    int pos = atomicAdd(&cursor[dst[e]], 1);
    float r[RECW];
    r[0] = __int_as_float(src[e]);
    const float2* f0 = (const float2*)(ef0 + (long)e * 6);
    float2 a = f0[0], b = f0[1], c = f0[2];
    r[1] = a.x; r[2] = a.y; r[3] = b.x; r[4] = b.y; r[5] = c.x; r[6] = c.y;
    r[7] = ef1[(long)e * 3 + 0];
    r[8] = ef1[(long)e * 3 + 1];
    r[9] = ef1[(long)e * 3 + 2];
    float* out = recF + (long)pos * RECW;
#pragma unroll
    for (int j = 0; j < RECW; ++j) out[j] = r[j];
}

__global__ __launch_bounds__(256) void gather_rec_kernel(
    const float* __restrict__ node_feats,
    const float* __restrict__ recF, const int* __restrict__ offsets,
    const float* __restrict__ We0, const float* __restrict__ be0,
    const float* __restrict__ We1, const float* __restrict__ be1,
    float* __restrict__ agg)
{
    int wave = threadIdx.x >> 6;
    int lane = threadIdx.x & 63;
    int n = blockIdx.x * 4 + wave;
    if (n >= N_NODES) return;

    float2 w[9];
#pragma unroll
    for (int k = 0; k < 6; ++k) w[k] = ((const float2*)We0)[k * 64 + lane];
#pragma unroll
    for (int k = 0; k < 3; ++k) w[6 + k] = ((const float2*)We1)[k * 64 + lane];
    float2 bias;
    {
        float2 a = ((const float2*)be0)[lane];
        float2 b = ((const float2*)be1)[lane];
        bias.x = a.x + b.x; bias.y = a.y + b.y;
    }

    int beg = offsets[n];
    int end = offsets[n + 1];
    int col = lane % 10;
    float colsum = 0.f;
    float2 acc = make_float2(0.f, 0.f);
    const float2* nf2 = (const float2*)node_feats;

    for (int base = beg; base < end; base += 6) {
        int m = end - base; if (m > 6) m = 6;
        float v = 0.f;
        if (lane < m * 10) v = recF[(long)base * RECW + lane];
        if (col != 0) colsum += v;
#pragma unroll 6
        for (int j = 0; j < 6; ++j) {
            if (j >= m) break;
            int s = __float_as_int(__shfl(v, j * 10));
            float2 nf = nf2[(long)s * 64 + lane];
            acc.x += nf.x;
            acc.y += nf.y;
        }
    }

    float s1 = colsum + __shfl(colsum, lane + 30);
    float tot = s1 + __shfl(s1, lane + 10) + __shfl(s1, lane + 20);

    float deg = (float)(end - beg);
    float2 emb = make_float2(deg * bias.x, deg * bias.y);
#pragma unroll
    for (int k = 0; k < 9; ++k) {
        float fk = __shfl(tot, k + 1);
        emb.x = fmaf(fk, w[k].x, emb.x);
        emb.y = fmaf(fk, w[k].y, emb.y);
    }
    acc.x += emb.x;
    acc.y += emb.y;
    ((float2*)agg)[(long)n * 64 + lane] = acc;
}

// =================== MIDDLE tier (int2 path) ===================
__global__ __launch_bounds__(256) void scatter_kernel(
    const int* __restrict__ src, const int* __restrict__ dst,
    int* __restrict__ cursor, int2* __restrict__ sorted)
{
    int e = blockIdx.x * 256 + threadIdx.x;
    if (e >= N_EDGES) return;
    int t = dst[e];
    int pos = atomicAdd(&cursor[t], 1);
    sorted[pos] = make_int2(src[e], e);
}

__global__ __launch_bounds__(256) void gather_reduce_kernel(
    const float* __restrict__ node_feats,
    const float* __restrict__ ef0, const float* __restrict__ ef1,
    const int2* __restrict__ sorted, const int* __restrict__ offsets,
    const float* __restrict__ We0, const float* __restrict__ be0,
    const float* __restrict__ We1, const float* __restrict__ be1,
    float* __restrict__ agg)
{
    int wave = threadIdx.x >> 6;
    int lane = threadIdx.x & 63;
    int n = blockIdx.x * 4 + wave;
    if (n >= N_NODES) return;

    float2 w0[6], w1[3];
#pragma unroll
    for (int k = 0; k < 6; ++k) w0[k] = ((const float2*)We0)[k * 64 + lane];
#pragma unroll
    for (int k = 0; k < 3; ++k) w1[k] = ((const float2*)We1)[k * 64 + lane];
    float2 bias;
    {
        float2 a = ((const float2*)be0)[lane];
        float2 b = ((const float2*)be1)[lane];
        bias.x = a.x + b.x; bias.y = a.y + b.y;
    }

    int beg = offsets[n];
    int end = offsets[n + 1];
    float2 acc = make_float2(0.f, 0.f);

    for (int i = beg; i < end; ++i) {
        int2 se = sorted[i];
        float f = 0.f;
        if (lane < 6)      f = ef0[(long)se.y * 6 + lane];
        else if (lane < 9) f = ef1[(long)se.y * 3 + (lane - 6)];

        float2 emb = bias;
#pragma unroll
        for (int k = 0; k < 6; ++k) {
            float fk = __shfl(f, k);
            emb.x = fmaf(fk, w0[k].x, emb.x);
            emb.y = fmaf(fk, w0[k].y, emb.y);
        }
#pragma unroll
        for (int k = 0; k < 3; ++k) {
            float fk = __shfl(f, 6 + k);
            emb.x = fmaf(fk, w1[k].x, emb.x);
            emb.y = fmaf(fk, w1[k].y, emb.y);
        }
        float2 nf = ((const float2*)node_feats)[(long)se.x * 64 + lane];
        acc.x += nf.x + emb.x;
        acc.y += nf.y + emb.y;
    }
    ((float2*)agg)[(long)n * 64 + lane] = acc;
}

// =================== LAST resort: atomic path ===================
__global__ __launch_bounds__(256) void edge_scatter_kernel(
    const float* __restrict__ node_feats,
    const float* __restrict__ ef0,
    const float* __restrict__ ef1,
    const int* __restrict__ src,
    const int* __restrict__ dst,
    const float* __restrict__ We0, const float* __restrict__ be0,
    const float* __restrict__ We1, const float* __restrict__ be1,
    float* __restrict__ agg)
{
    __shared__ float wS[10 * EMB];
    int tid = threadIdx.x;
    for (int i = tid; i < 6 * EMB; i += 256) wS[i] = We0[i];
    for (int i = tid; i < 3 * EMB; i += 256) wS[6 * EMB + i] = We1[i];
    if (tid < EMB) wS[9 * EMB + tid] = be0[tid] + be1[tid];
    __syncthreads();

    int e = blockIdx.x * 2 + (tid >> 7);
    if (e >= N_EDGES) return;
    int d = tid & 127;
    int s = src[e];
    int t = dst[e];
    const float* f0 = ef0 + (long)e * 6;
    const float* f1 = ef1 + (long)e * 3;

    float emb = wS[9 * EMB + d];
#pragma unroll
    for (int k = 0; k < 6; ++k) emb = fmaf(f0[k], wS[k * EMB + d], emb);
#pragma unroll
    for (int k = 0; k < 3; ++k) emb = fmaf(f1[k], wS[6 * EMB + k * EMB + d], emb);

    float val = node_feats[(long)s * EMB + d] + emb;
    atomicAdd(&agg[(long)t * EMB + d], val);
}

// =================== weight fragment prep (bf16, MFMA B-layout) ===========
// w1f: ((nt*4+ks)*64+lane)*8+i = bf16(W1[ks*32+(lane>>4)*8+i][nt*16+(lane&15)])
// w2f: ((nt*8+ks)*64+lane)*8+i = bf16(W2[ks*32+(lane>>4)*8+i][nt*16+(lane&15)])
__global__ __launch_bounds__(256) void prep_frags_kernel(
    const float* __restrict__ W1, const float* __restrict__ W2,
    ushort* __restrict__ w1f, ushort* __restrict__ w2f)
{
    int idx = blockIdx.x * 256 + threadIdx.x;   // 0..65535
    int i = idx & 7;
    int lane = (idx >> 3) & 63;
    int kloc = ((lane >> 4) << 3) + i;
    int nloc = lane & 15;
    if (idx < 32768) {
        int ks = (idx >> 9) & 3, nt = idx >> 11;
        w1f[idx] = f2bf(W1[(ks * 32 + kloc) * 256 + nt * 16 + nloc]);
    } else {
        int j = idx - 32768;
        int ks = (j >> 9) & 7, nt = j >> 12;
        w2f[j] = f2bf(W2[(ks * 32 + kloc) * 128 + nt * 16 + nloc]);
    }
}

// =================== fused MFMA MLP + BN stats ===================
// 32 rows/block, 4 waves. GEMM1: [32x128]@[128x256] relu; GEMM2: [32x256]@[256x128].
__global__ __launch_bounds__(256) void mlp_mfma_kernel(
    float* __restrict__ h,
    const ushort* __restrict__ w1f, const ushort* __restrict__ w2f,
    const float* __restrict__ b1, const float* __restrict__ b2,
    float* __restrict__ stats)
{
    __shared__ __align__(16) char aggS[32 * 256];   // 32 rows x 128 bf16, swizzled
    __shared__ __align__(16) char h1S[32 * 512];    // 32 rows x 256 bf16, swizzled

    int tid = threadIdx.x;
    int lane = tid & 63;
    int wv = tid >> 6;
    long base = (long)blockIdx.x * 32;

    // ---- stage agg -> bf16 LDS (swizzled) ----
    for (int c = tid; c < 32 * 16; c += 256) {     // 16B chunks
        int row = c >> 4, j = c & 15;
        const float4* g = (const float4*)(h + (base + row) * EMB + j * 8);
        float4 x = g[0], y = g[1];
        union { ushort u[8]; short8 v; } pk;
        pk.u[0] = f2bf(x.x); pk.u[1] = f2bf(x.y); pk.u[2] = f2bf(x.z); pk.u[3] = f2bf(x.w);
        pk.u[4] = f2bf(y.x); pk.u[5] = f2bf(y.y); pk.u[6] = f2bf(y.z); pk.u[7] = f2bf(y.w);
        *(short8*)&aggS[row * 256 + ((j * 16) ^ ((row & 7) << 4))] = pk.v;
    }
    __syncthreads();

    // ---- GEMM1: wave wv owns n-tiles [wv*4, wv*4+4) ----
    floatx4 acc1[2][4];
#pragma unroll
    for (int nt = 0; nt < 4; ++nt) {
        float bias = b1[(wv * 4 + nt) * 16 + (lane & 15)];
#pragma unroll
        for (int mt = 0; mt < 2; ++mt)
            acc1[mt][nt] = (floatx4){bias, bias, bias, bias};
    }
    int swz = (lane & 7) << 4;
#pragma unroll
    for (int ks = 0; ks < 4; ++ks) {
        int kb = ks * 64 + ((lane >> 4) << 4);
        short8 a0 = *(const short8*)&aggS[(lane & 15) * 256 + (kb ^ swz)];
        short8 a1 = *(const short8*)&aggS[(16 + (lane & 15)) * 256 + (kb ^ swz)];
#pragma unroll
        for (int nt = 0; nt < 4; ++nt) {
            short8 b = *(const short8*)&w1f[(((wv * 4 + nt) * 4 + ks) * 64 + lane) * 8];
            acc1[0][nt] = __builtin_amdgcn_mfma_f32_16x16x32_bf16(a0, b, acc1[0][nt], 0, 0, 0);
            acc1[1][nt] = __builtin_amdgcn_mfma_f32_16x16x32_bf16(a1, b, acc1[1][nt], 0, 0, 0);
        }
    }
    // relu -> bf16 -> h1S (swizzled)
#pragma unroll
    for (int mt = 0; mt < 2; ++mt)
#pragma unroll
        for (int nt = 0; nt < 4; ++nt)
#pragma unroll
            for (int i = 0; i < 4; ++i) {
                int row = mt * 16 + ((lane >> 4) << 2) + i;
                int col = (wv * 4 + nt) * 16 + (lane & 15);
                float v = fmaxf(acc1[mt][nt][i], 0.f);
                *(ushort*)&h1S[row * 512 + ((2 * col) ^ ((row & 7) << 4))] = f2bf(v);
            }
    __syncthreads();

    // ---- GEMM2: wave wv owns n-tiles [wv*2, wv*2+2) ----
    floatx4 acc2[2][2];
#pragma unroll
    for (int nt = 0; nt < 2; ++nt) {
        float bias = b2[(wv * 2 + nt) * 16 + (lane & 15)];
#pragma unroll
        for (int mt = 0; mt < 2; ++mt)
            acc2[mt][nt] = (floatx4){bias, bias, bias, bias};
    }
#pragma unroll
    for (int ks = 0; ks < 8; ++ks) {
        int kb = ks * 64 + ((lane >> 4) << 4);
        short8 a0 = *(const short8*)&h1S[(lane & 15) * 512 + (kb ^ swz)];
        short8 a1 = *(const short8*)&h1S[(16 + (lane & 15)) * 512 + (kb ^ swz)];
#pragma unroll
        for (int nt = 0; nt < 2; ++nt) {
            short8 b = *(const short8*)&w2f[(((wv * 2 + nt) * 8 + ks) * 64 + lane) * 8];
            acc2[0][nt] = __builtin_amdgcn_mfma_f32_16x16x32_bf16(a0, b, acc2[0][nt], 0, 0, 0);
            acc2[1][nt] = __builtin_amdgcn_mfma_f32_16x16x32_bf16(a1, b, acc2[1][nt], 0, 0, 0);
        }
    }

    // ---- epilogue: store + per-column stats ----
    float s[2] = {0.f, 0.f}, s2[2] = {0.f, 0.f};
#pragma unroll
    for (int nt = 0; nt < 2; ++nt) {
        int col = (wv * 2 + nt) * 16 + (lane & 15);
#pragma unroll
        for (int mt = 0; mt < 2; ++mt)
#pragma unroll
            for (int i = 0; i < 4; ++i) {
                int row = mt * 16 + ((lane >> 4) << 2) + i;
                float v = acc2[mt][nt][i];
                h[(base + row) * EMB + col] = v;
                s[nt] += v;
                s2[nt] = fmaf(v, v, s2[nt]);
            }
    }
#pragma unroll
    for (int nt = 0; nt < 2; ++nt) {
        s[nt] += __shfl_xor(s[nt], 16);
        s[nt] += __shfl_xor(s[nt], 32);
        s2[nt] += __shfl_xor(s2[nt], 16);
        s2[nt] += __shfl_xor(s2[nt], 32);
    }
    if (lane < 16) {
        float* slab = stats + (blockIdx.x & (NSLAB - 1)) * (2 * EMB);
#pragma unroll
        for (int nt = 0; nt < 2; ++nt) {
            int col = (wv * 2 + nt) * 16 + lane;
            atomicAdd(&slab[col], s[nt]);
            atomicAdd(&slab[EMB + col], s2[nt]);
        }
    }
}

// =================== fp32 MLP fallback (atomic tier only) ===================
__global__ __launch_bounds__(256) void mlp_kernel(
    float* __restrict__ h,
    const float* __restrict__ W1, const float* __restrict__ b1,
    const float* __restrict__ W2, const float* __restrict__ b2,
    float* __restrict__ stats)
{
    __shared__ float aggS[BM][EMB];
    __shared__ float h1S[BM][2 * EMB];
    __shared__ float sredS[256];
    __shared__ float s2redS[256];

    int tid = threadIdx.x;
    long base = (long)blockIdx.x * BM;

    for (int i = tid; i < BM * EMB; i += 256)
        aggS[i >> 7][i & 127] = h[base * EMB + i];
    __syncthreads();

    {
        float acc[BM];
        float bias = b1[tid];
#pragma unroll
        for (int r = 0; r < BM; ++r) acc[r] = bias;
        for (int k = 0; k < EMB; ++k) {
            float w = W1[k * (2 * EMB) + tid];
#pragma unroll
            for (int r = 0; r < BM; ++r) acc[r] = fmaf(aggS[r][k], w, acc[r]);
        }
#pragma unroll
        for (int r = 0; r < BM; ++r) h1S[r][tid] = fmaxf(acc[r], 0.0f);
    }
    __syncthreads();

    {
        int c = tid & 127;
        int half = tid >> 7;
        float acc[8];
        float bias = b2[c];
#pragma unroll
        for (int r = 0; r < 8; ++r) acc[r] = bias;
        for (int k = 0; k < 2 * EMB; ++k) {
            float w = W2[k * EMB + c];
#pragma unroll
            for (int r = 0; r < 8; ++r) acc[r] = fmaf(h1S[half * 8 + r][k], w, acc[r]);
        }
        float s = 0.f, s2 = 0.f;
#pragma unroll
        for (int r = 0; r < 8; ++r) {
            h[(base + half * 8 + r) * EMB + c] = acc[r];
            s += acc[r];
            s2 = fmaf(acc[r], acc[r], s2);
        }
        sredS[tid] = s;
        s2redS[tid] = s2;
    }
    __syncthreads();
    if (tid < 128) {
        float s = sredS[tid] + sredS[tid + 128];
        float s2 = s2redS[tid] + s2redS[tid + 128];
        float* slab = stats + (blockIdx.x & (NSLAB - 1)) * (2 * EMB);
        atomicAdd(&slab[tid], s);
        atomicAdd(&slab[EMB + tid], s2);
    }
}

__global__ __launch_bounds__(128) void bn_finalize_kernel(
    const float* __restrict__ stats,
    const float* __restrict__ gamma, const float* __restrict__ beta,
    float* __restrict__ scaleshift)
{
    int c = threadIdx.x;
    float s = 0.f, s2 = 0.f;
    for (int b = 0; b < NSLAB; ++b) {
        s += stats[b * (2 * EMB) + c];
        s2 += stats[b * (2 * EMB) + EMB + c];
    }
    float mean = s / (float)N_NODES;
    float var = s2 / (float)N_NODES - mean * mean;
    float sc = gamma[c] * rsqrtf(var + BN_EPS);
    scaleshift[c] = sc;
    scaleshift[EMB + c] = beta[c] - mean * sc;
}

__global__ __launch_bounds__(256) void bn_apply_kernel(
    float* __restrict__ h, const float* __restrict__ scaleshift)
{
    __shared__ float scS[EMB], shS[EMB];
    if (threadIdx.x < EMB) {
        scS[threadIdx.x] = scaleshift[threadIdx.x];
        shS[threadIdx.x] = scaleshift[EMB + threadIdx.x];
    }
    __syncthreads();
    long total = (long)N_NODES * EMB / 4;
    long stride = (long)gridDim.x * blockDim.x;
    for (long i = (long)blockIdx.x * blockDim.x + threadIdx.x; i < total; i += stride) {
        float4 v = ((float4*)h)[i];
        int c = (int)((i * 4) & 127);
        v.x = fmaf(v.x, scS[c + 0], shS[c + 0]);
        v.y = fmaf(v.y, scS[c + 1], shS[c + 1]);
        v.z = fmaf(v.z, scS[c + 2], shS[c + 2]);
        v.w = fmaf(v.w, scS[c + 3], shS[c + 3]);
        ((float4*)h)[i] = v;
    }
}

extern "C" void kernel_launch(void* const* d_in, const int* in_sizes, int n_in,
                              void* d_out, int out_size, void* d_ws, size_t ws_size,
                              hipStream_t stream) {
    const float* node_feats = (const float*)d_in[0];
    const float* ef0 = (const float*)d_in[1];
    const float* ef1 = (const float*)d_in[2];
    const int* src = (const int*)d_in[3];
    const int* dst = (const int*)d_in[4];
    const float* We0 = (const float*)d_in[5];
    const float* be0 = (const float*)d_in[6];
    const float* We1 = (const float*)d_in[7];
    const float* be1 = (const float*)d_in[8];
    const float* W1 = (const float*)d_in[9];
    const float* b1 = (const float*)d_in[10];
    const float* W2 = (const float*)d_in[11];
    const float* b2 = (const float*)d_in[12];
    const float* gamma = (const float*)d_in[13];
    const float* beta = (const float*)d_in[14];

    float* out = (float*)d_out;

    // ws layout: stats | scaleshift | counts | offsets | cursor | blockSums | payload
    float* stats = (float*)d_ws;
    float* scaleshift = stats + NSLAB * 2 * EMB;
    int* counts = (int*)(scaleshift + 256);
    int* offsets = counts + NPAD;
    int* cursor = offsets + NPAD;
    int* blockSums = cursor + NPAD;
    float* recF = (float*)(blockSums + 256);             // E*10 floats (64 MB)
    int2* sorted = (int2*)(blockSums + 256);             // E int2 (12.8 MB)
    // frag buffers: rec tier reuses recF region (dead after gather);
    // middle tier places them after `sorted`.
    ushort* w1f_rec = (ushort*)recF;
    ushort* w2f_rec = w1f_rec + 32768;
    ushort* w1f_mid = (ushort*)(sorted + N_EDGES);
    ushort* w2f_mid = w1f_mid + 32768;

    size_t needRec = (size_t)((char*)(recF + (size_t)N_EDGES * RECW) - (char*)d_ws);
    size_t needSorted = (size_t)((char*)(w2f_mid + 32768) - (char*)d_ws);

    hipMemsetAsync(stats, 0, (size_t)NSLAB * 2 * EMB * sizeof(float), stream);

    if (ws_size >= needSorted) {
        hipMemsetAsync(counts, 0, (size_t)N_NODES * sizeof(int), stream);
        hist_kernel<<<(N_EDGES + 255) / 256, 256, 0, stream>>>(dst, counts);
        scan_blocksum_kernel<<<NB_SCAN, SCAN_BLK, 0, stream>>>(counts, blockSums);
        scan_blockoffsets_kernel<<<1, 256, 0, stream>>>(blockSums);
        scan_final_kernel<<<NB_SCAN, SCAN_BLK, 0, stream>>>(counts, blockSums, offsets, cursor);
        ushort* w1f; ushort* w2f;
        if (ws_size >= needRec) {
            scatter_rec_kernel<<<(N_EDGES + 255) / 256, 256, 0, stream>>>(
                src, dst, ef0, ef1, cursor, recF);
            gather_rec_kernel<<<(N_NODES + 3) / 4, 256, 0, stream>>>(
                node_feats, recF, offsets, We0, be0, We1, be1, out);
            w1f = w1f_rec; w2f = w2f_rec;
        } else {
            scatter_kernel<<<(N_EDGES + 255) / 256, 256, 0, stream>>>(src, dst, cursor, sorted);
            gather_reduce_kernel<<<(N_NODES + 3) / 4, 256, 0, stream>>>(
                node_feats, ef0, ef1, sorted, offsets, We0, be0, We1, be1, out);
            w1f = w1f_mid; w2f = w2f_mid;
        }
        prep_frags_kernel<<<256, 256, 0, stream>>>(W1, W2, w1f, w2f);
        mlp_mfma_kernel<<<N_NODES / 32, 256, 0, stream>>>(out, w1f, w2f, b1, b2, stats);
    } else {
        hipMemsetAsync(d_out, 0, (size_t)N_NODES * EMB * sizeof(float), stream);
        edge_scatter_kernel<<<N_EDGES / 2, 256, 0, stream>>>(
            node_feats, ef0, ef1, src, dst, We0, be0, We1, be1, out);
        mlp_kernel<<<N_NODES / BM, 256, 0, stream>>>(out, W1, b1, W2, b2, stats);
    }

    bn_finalize_kernel<<<1, 128, 0, stream>>>(stats, gamma, beta, scaleshift);
    bn_apply_kernel<<<2048, 256, 0, stream>>>(out, scaleshift);
}